// Round 4
// baseline (262.448 us; speedup 1.0000x reference)
//
#include <hip/hip_runtime.h>
#include <hip/hip_cooperative_groups.h>
#include <hip/hip_bf16.h>
#include <stdint.h>

#define UNITS 1024
#define IDIM  512
#define BATCH 2048
#define KTOT  1536   // UNITS + IDIM
#define NGATE 4096   // 4*UNITS
#define BK    64
#define NITER (KTOT / BK)   // 24

typedef short bf16x8 __attribute__((ext_vector_type(8)));   // 8 bf16 = 4 VGPRs
typedef float f32x4  __attribute__((ext_vector_type(4)));

#define AS3(p) ((__attribute__((address_space(3))) void*)(p))
#define AS1(p) ((const __attribute__((address_space(1))) void*)(p))

union P8 { bf16x8 v; __hip_bfloat16 e[8]; };

// ---------------------------------------------------------------------------
// prep tasks. 4608 total: [0,1536) cast-concat A = bf16(concat[h,x]);
// [1536,4608) transpose W fp32 [1536][4096] -> Wt bf16 [4096][1536].
// Shared by the standalone prep kernel (fallback) and the fused kernel.
// ---------------------------------------------------------------------------
#define NTASK_A 1536
#define NTASK_W 3072
#define NTASK   (NTASK_A + NTASK_W)

__device__ __forceinline__ void a_task(int task, int tid,
    const float* x, const float* h, __hip_bfloat16* A) {
  const int id = task * 256 + tid;
  const int r = id / (KTOT / 8);
  const int k = (id % (KTOT / 8)) * 8;
  const float* src = (k < UNITS) ? h + (size_t)r * UNITS + k
                                 : x + (size_t)r * IDIM + (k - UNITS);
  const float4 v0 = ((const float4*)src)[0];
  const float4 v1 = ((const float4*)src)[1];
  P8 o;
  o.e[0] = __float2bfloat16(v0.x); o.e[1] = __float2bfloat16(v0.y);
  o.e[2] = __float2bfloat16(v0.z); o.e[3] = __float2bfloat16(v0.w);
  o.e[4] = __float2bfloat16(v1.x); o.e[5] = __float2bfloat16(v1.y);
  o.e[6] = __float2bfloat16(v1.z); o.e[7] = __float2bfloat16(v1.w);
  *(bf16x8*)(A + (size_t)r * KTOT + k) = o.v;
}

// caller must __syncthreads() BEFORE calling (tile WAR vs previous task)
__device__ __forceinline__ void w_task(int b, int tid,
    const float* W, __hip_bfloat16* Wt, float (*tile)[65]) {
  const int kb = b >> 7;                // 0..23
  const int nb = b & 127;               // 0..127
  const int k0 = kb * 64, n0 = nb * 32;
  const int n4 = (tid & 7) * 4;
  const int kk = tid >> 3;              // 0..31
#pragma unroll
  for (int rr = 0; rr < 64; rr += 32) {
    const float4 v = *(const float4*)(W + (size_t)(k0 + kk + rr) * NGATE + n0 + n4);
    tile[n4 + 0][kk + rr] = v.x; tile[n4 + 1][kk + rr] = v.y;
    tile[n4 + 2][kk + rr] = v.z; tile[n4 + 3][kk + rr] = v.w;
  }
  __syncthreads();
  const int n  = tid >> 3;
  const int k8 = (tid & 7) * 8;
  P8 o;
#pragma unroll
  for (int j = 0; j < 8; ++j) o.e[j] = __float2bfloat16(tile[n][k8 + j]);
  *(bf16x8*)(Wt + (size_t)(n0 + n) * KTOT + k0 + k8) = o.v;
}

// ---------------------------------------------------------------------------
// Fused cooperative kernel: prep phase (9 tasks/block over 512 blocks) ->
// __threadfence + grid.sync (device-scope release/acquire covers cross-XCD
// L2 non-coherence, G16) -> R0 gemm VERBATIM (the proven 120.8 us config:
// 2 blocks/CU, 4 waves, 128x32-unit tile, acc[4][4], 8-slot XOR swizzle
// measured 0 conflicts, single-__syncthreads dbuf loop). R1-R3 established:
// counted-vmcnt = neutral, occupancy x2 = neutral, bigger wave tile at
// 1 block/CU = regression. The only remaining lever is the kernel boundary.
// ---------------------------------------------------------------------------
__global__ __launch_bounds__(256, 2) void lstm_all(
    const float* __restrict__ x, const float* __restrict__ h,
    const float* __restrict__ W, const float* __restrict__ c_tm1,
    __hip_bfloat16* A, __hip_bfloat16* Wt, float* out) {
  __shared__ __attribute__((aligned(128))) char lds[4 * 16384];  // A0 A1 B0 B1

  const int tid = threadIdx.x;

  // ---- phase 1: prep (tasks uniform per block; barriers non-divergent) ----
  {
    float (*tile)[65] = (float (*)[65])lds;   // 8.3 KB overlay, reused below
#pragma unroll 1
    for (int t9 = 0; t9 < 9; ++t9) {
      const int task = blockIdx.x * 9 + t9;   // 512*9 = 4608 = NTASK
      if (task < NTASK_A) {
        a_task(task, tid, x, h, A);
      } else {
        __syncthreads();                      // WAR on tile vs previous task
        w_task(task - NTASK_A, tid, W, Wt, tile);
      }
    }
  }
  __threadfence();                            // release A/Wt to device scope
  cooperative_groups::this_grid().sync();     // all prep done, acquire

  // ---- phase 2: gemm + fused LSTM (R0 verbatim) ----
  const int w    = tid >> 6;     // wave 0..3 (uniform)
  const int lane = tid & 63;
  const int quad = lane >> 4;
  const int m16  = lane & 15;
  const int wr   = w >> 1;       // row half (0,1)
  const int wu   = w & 1;        // unit half (0,1)

  const int mb = blockIdx.x >> 5;   // 0..15
  const int ub = blockIdx.x & 31;   // 0..31  (XCD = ub % 8)
  const int m0 = mb * 128;
  const int u0 = ub * 32;

  // Staging: 2048 16B chunks per iter (A 1024 + B 1024) / 256 thr = 8 each.
  const __hip_bfloat16* ptr[8];
  int dst[8];
#pragma unroll
  for (int s = 0; s < 8; ++s) {
    const int q  = s * 4 + w;              // wave-uniform 0..31
    const int ci = (q & 15) * 64 + lane;   // chunk 0..1023 within tile
    const int row = ci >> 3;               // 0..127
    const int k8  = (ci & 7) ^ (row & 7);  // source-side swizzle
    if (q < 16) {   // A tile
      ptr[s] = A + (size_t)(m0 + row) * KTOT + k8 * 8;
      dst[s] = q * 1024;                   // within A buffer
    } else {        // B tile: virtual col row -> Wt row
      const int wrow = ((row >> 5) << 10) + u0 + (row & 31);
      ptr[s] = Wt + (size_t)wrow * KTOT + k8 * 8;
      dst[s] = 32768 + (q - 16) * 1024;    // within B buffer 0
    }
  }

  f32x4 acc[4][4];
#pragma unroll
  for (int i = 0; i < 4; ++i)
#pragma unroll
    for (int g = 0; g < 4; ++g) {
      f32x4 z = {0.f, 0.f, 0.f, 0.f};
      acc[i][g] = z;
    }

  // prologue: stage iter 0 into buffer 0
#pragma unroll
  for (int s = 0; s < 8; ++s)
    __builtin_amdgcn_global_load_lds(AS1(ptr[s]), AS3(lds + dst[s]), 16, 0, 0);
  __syncthreads();

  for (int it = 0; it < NITER; ++it) {
    const int cur = it & 1;
    const int nxt = cur ^ 1;
    if (it < NITER - 1) {
      const int koff = (it + 1) * BK;
#pragma unroll
      for (int s = 0; s < 8; ++s)
        __builtin_amdgcn_global_load_lds(AS1(ptr[s] + koff),
                                         AS3(lds + dst[s] + nxt * 16384), 16, 0, 0);
    }
    const char* abuf = lds + cur * 16384;
    const char* bbuf = lds + 32768 + cur * 16384;
#pragma unroll
    for (int t = 0; t < 2; ++t) {
      bf16x8 a[4], b[4];
#pragma unroll
      for (int i = 0; i < 4; ++i) {
        const int row  = wr * 64 + i * 16 + m16;
        const int slot = (t * 4 + quad) ^ (row & 7);
        a[i] = *(const bf16x8*)(abuf + (row * 8 + slot) * 16);
      }
#pragma unroll
      for (int g = 0; g < 4; ++g) {
        const int vr   = g * 32 + wu * 16 + m16;
        const int slot = (t * 4 + quad) ^ (vr & 7);
        b[g] = *(const bf16x8*)(bbuf + (vr * 8 + slot) * 16);
      }
#pragma unroll
      for (int g = 0; g < 4; ++g)
#pragma unroll
        for (int i = 0; i < 4; ++i)
          acc[i][g] = __builtin_amdgcn_mfma_f32_16x16x32_bf16(a[i], b[g], acc[i][g], 0, 0, 0);
    }
    __syncthreads();   // drains prefetch writes + fences reads of `cur`
  }

  // fused LSTM epilogue -- all 4 gates in-lane
  const int u = u0 + wu * 16 + m16;
#pragma unroll
  for (int i = 0; i < 4; ++i)
#pragma unroll
    for (int reg = 0; reg < 4; ++reg) {
      const int r = m0 + wr * 64 + i * 16 + quad * 4 + reg;
      const float z0 = acc[i][0][reg];   // gate i
      const float z1 = acc[i][1][reg];   // gate f
      const float z2 = acc[i][2][reg];   // c_tilde
      const float z3 = acc[i][3][reg];   // gate o
      const float ig = 1.f / (1.f + __expf(-z0));
      const float fg = 1.f / (1.f + __expf(-z1));
      const float ct = 1.f - 2.f / (__expf(2.f * z2) + 1.f);   // tanh, inf-safe
      const float og = 1.f / (1.f + __expf(-z3));
      const float cc = fg * c_tm1[(size_t)r * UNITS + u] + ig * ct;
      const float hh = og * (1.f - 2.f / (__expf(2.f * cc) + 1.f));
      out[(size_t)r * UNITS + u] = hh;
      out[(size_t)BATCH * UNITS + (size_t)r * UNITS + u] = cc;
    }
}

// ---------------------------------------------------------------------------
// Standalone fallback pair (R0 verbatim) — used if cooperative launch is
// rejected (e.g. by graph capture). Guarantees exact-baseline behavior.
// ---------------------------------------------------------------------------
__global__ __launch_bounds__(256) void prep(
    const float* __restrict__ x, const float* __restrict__ h,
    const float* __restrict__ W,
    __hip_bfloat16* __restrict__ A, __hip_bfloat16* __restrict__ Wt) {
  __shared__ float tile[32][65];
  const int tid = threadIdx.x;
  if (blockIdx.x < NTASK_A) a_task(blockIdx.x, tid, x, h, A);
  else                      w_task(blockIdx.x - NTASK_A, tid, W, Wt, tile);
}

__global__ __launch_bounds__(256, 2) void lstm_gemm(
    const __hip_bfloat16* __restrict__ A,
    const __hip_bfloat16* __restrict__ Wt,
    const float* __restrict__ c_tm1,
    float* __restrict__ out) {
  __shared__ __attribute__((aligned(128))) char lds[4 * 16384];

  const int tid  = threadIdx.x;
  const int w    = tid >> 6;
  const int lane = tid & 63;
  const int quad = lane >> 4;
  const int m16  = lane & 15;
  const int wr   = w >> 1;
  const int wu   = w & 1;

  const int mb = blockIdx.x >> 5;
  const int ub = blockIdx.x & 31;
  const int m0 = mb * 128;
  const int u0 = ub * 32;

  const __hip_bfloat16* ptr[8];
  int dst[8];
#pragma unroll
  for (int s = 0; s < 8; ++s) {
    const int q  = s * 4 + w;
    const int ci = (q & 15) * 64 + lane;
    const int row = ci >> 3;
    const int k8  = (ci & 7) ^ (row & 7);
    if (q < 16) {
      ptr[s] = A + (size_t)(m0 + row) * KTOT + k8 * 8;
      dst[s] = q * 1024;
    } else {
      const int wrow = ((row >> 5) << 10) + u0 + (row & 31);
      ptr[s] = Wt + (size_t)wrow * KTOT + k8 * 8;
      dst[s] = 32768 + (q - 16) * 1024;
    }
  }

  f32x4 acc[4][4];
#pragma unroll
  for (int i = 0; i < 4; ++i)
#pragma unroll
    for (int g = 0; g < 4; ++g) {
      f32x4 z = {0.f, 0.f, 0.f, 0.f};
      acc[i][g] = z;
    }

#pragma unroll
  for (int s = 0; s < 8; ++s)
    __builtin_amdgcn_global_load_lds(AS1(ptr[s]), AS3(lds + dst[s]), 16, 0, 0);
  __syncthreads();

  for (int it = 0; it < NITER; ++it) {
    const int cur = it & 1;
    const int nxt = cur ^ 1;
    if (it < NITER - 1) {
      const int koff = (it + 1) * BK;
#pragma unroll
      for (int s = 0; s < 8; ++s)
        __builtin_amdgcn_global_load_lds(AS1(ptr[s] + koff),
                                         AS3(lds + dst[s] + nxt * 16384), 16, 0, 0);
    }
    const char* abuf = lds + cur * 16384;
    const char* bbuf = lds + 32768 + cur * 16384;
#pragma unroll
    for (int t = 0; t < 2; ++t) {
      bf16x8 a[4], b[4];
#pragma unroll
      for (int i = 0; i < 4; ++i) {
        const int row  = wr * 64 + i * 16 + m16;
        const int slot = (t * 4 + quad) ^ (row & 7);
        a[i] = *(const bf16x8*)(abuf + (row * 8 + slot) * 16);
      }
#pragma unroll
      for (int g = 0; g < 4; ++g) {
        const int vr   = g * 32 + wu * 16 + m16;
        const int slot = (t * 4 + quad) ^ (vr & 7);
        b[g] = *(const bf16x8*)(bbuf + (vr * 8 + slot) * 16);
      }
#pragma unroll
      for (int g = 0; g < 4; ++g)
#pragma unroll
        for (int i = 0; i < 4; ++i)
          acc[i][g] = __builtin_amdgcn_mfma_f32_16x16x32_bf16(a[i], b[g], acc[i][g], 0, 0, 0);
    }
    __syncthreads();
  }

  const int u = u0 + wu * 16 + m16;
#pragma unroll
  for (int i = 0; i < 4; ++i)
#pragma unroll
    for (int reg = 0; reg < 4; ++reg) {
      const int r = m0 + wr * 64 + i * 16 + quad * 4 + reg;
      const float z0 = acc[i][0][reg];
      const float z1 = acc[i][1][reg];
      const float z2 = acc[i][2][reg];
      const float z3 = acc[i][3][reg];
      const float ig = 1.f / (1.f + __expf(-z0));
      const float fg = 1.f / (1.f + __expf(-z1));
      const float ct = 1.f - 2.f / (__expf(2.f * z2) + 1.f);
      const float og = 1.f / (1.f + __expf(-z3));
      const float cc = fg * c_tm1[(size_t)r * UNITS + u] + ig * ct;
      const float hh = og * (1.f - 2.f / (__expf(2.f * cc) + 1.f));
      out[(size_t)r * UNITS + u] = hh;
      out[(size_t)BATCH * UNITS + (size_t)r * UNITS + u] = cc;
    }
}

// ---------------------------------------------------------------------------
// Fallback (only if d_ws too small): naive fp32, correct but slow.
// ---------------------------------------------------------------------------
__global__ __launch_bounds__(256) void lstm_naive(
    const float* __restrict__ x, const float* __restrict__ h,
    const float* __restrict__ c_tm1, const float* __restrict__ W,
    float* __restrict__ out) {
  int idx = blockIdx.x * 256 + threadIdx.x;
  int r = idx / UNITS;
  int u = idx % UNITS;
  float z[4] = {0.f, 0.f, 0.f, 0.f};
  for (int k = 0; k < KTOT; ++k) {
    float a = (k < UNITS) ? h[(size_t)r * UNITS + k] : x[(size_t)r * IDIM + k - UNITS];
#pragma unroll
    for (int g = 0; g < 4; ++g)
      z[g] += a * W[(size_t)k * NGATE + g * UNITS + u];
  }
  float ig = 1.f / (1.f + __expf(-z[0]));
  float fg = 1.f / (1.f + __expf(-z[1]));
  float ct = 1.f - 2.f / (__expf(2.f * z[2]) + 1.f);
  float og = 1.f / (1.f + __expf(-z[3]));
  float cc = fg * c_tm1[(size_t)r * UNITS + u] + ig * ct;
  float hh = og * (1.f - 2.f / (__expf(2.f * cc) + 1.f));
  out[(size_t)r * UNITS + u] = hh;
  out[(size_t)BATCH * UNITS + (size_t)r * UNITS + u] = cc;
}

extern "C" void kernel_launch(void* const* d_in, const int* in_sizes, int n_in,
                              void* d_out, int out_size, void* d_ws, size_t ws_size,
                              hipStream_t stream) {
  const float* x = (const float*)d_in[0];   // [2048][512]
  const float* h = (const float*)d_in[1];   // [2048][1024]
  const float* c = (const float*)d_in[2];   // [2048][1024]
  const float* W = (const float*)d_in[3];   // [1536][4096]
  float* out = (float*)d_out;               // h then c, 2 x [2048][1024]

  const size_t needA  = (size_t)BATCH * KTOT * sizeof(__hip_bfloat16);  // 6.29 MB
  const size_t needWt = (size_t)NGATE * KTOT * sizeof(__hip_bfloat16);  // 12.58 MB
  if (ws_size < needA + needWt) {
    hipLaunchKernelGGL(lstm_naive, dim3((BATCH * UNITS) / 256), dim3(256), 0, stream,
                       x, h, c, W, out);
    return;
  }

  __hip_bfloat16* A  = (__hip_bfloat16*)d_ws;
  __hip_bfloat16* Wt = (__hip_bfloat16*)((char*)d_ws + needA);

  // Try the fused cooperative path (one kernel, no prep->gemm launch gap).
  void* args[7] = {(void*)&x, (void*)&h, (void*)&W, (void*)&c,
                   (void*)&A, (void*)&Wt, (void*)&out};
  hipError_t e = hipLaunchCooperativeKernel((void*)lstm_all, dim3(512), dim3(256),
                                            args, 0, stream);
  if (e != hipSuccess) {
    (void)hipGetLastError();   // clear error state; fall back to R0 two-kernel
    hipLaunchKernelGGL(prep, dim3(NTASK), dim3(256), 0, stream, x, h, W, A, Wt);
    hipLaunchKernelGGL(lstm_gemm, dim3(512), dim3(256), 0, stream, A, Wt, c, out);
  }
}

// Round 5
// 121.210 us; speedup vs baseline: 2.1652x; 2.1652x over previous
//
#include <hip/hip_runtime.h>
#include <hip/hip_bf16.h>
#include <stdint.h>

#define UNITS 1024
#define IDIM  512
#define BATCH 2048
#define KTOT  1536   // UNITS + IDIM
#define NGATE 4096   // 4*UNITS
#define BK    64
#define NITER (KTOT / BK)   // 24

typedef short bf16x8 __attribute__((ext_vector_type(8)));   // 8 bf16 = 4 VGPRs
typedef float f32x4  __attribute__((ext_vector_type(4)));

#define AS3(p) ((__attribute__((address_space(3))) void*)(p))
#define AS1(p) ((const __attribute__((address_space(1))) void*)(p))

union P8 { bf16x8 v; __hip_bfloat16 e[8]; };

// ---------------------------------------------------------------------------
// prep: blocks [0,1536) cast-concat A = bf16(concat[h,x]); blocks [1536,4608)
// transpose W fp32 [1536][4096] -> Wt bf16 [4096][1536] (k-contiguous rows).
// 4608 blocks (~18/CU queued) is what hides the strided-transpose latency --
// R4 proved collapsing this into few blocks is a 10x+ regression.
// ---------------------------------------------------------------------------
#define NBLK_A 1536
#define NBLK_T 3072

__global__ __launch_bounds__(256) void prep(
    const float* __restrict__ x, const float* __restrict__ h,
    const float* __restrict__ W,
    __hip_bfloat16* __restrict__ A, __hip_bfloat16* __restrict__ Wt) {
  __shared__ float tile[32][65];
  const int tid = threadIdx.x;
  if (blockIdx.x < NBLK_A) {
    const int id = blockIdx.x * 256 + tid;
    const int r = id / (KTOT / 8);
    const int k = (id % (KTOT / 8)) * 8;
    const float* src = (k < UNITS) ? h + (size_t)r * UNITS + k
                                   : x + (size_t)r * IDIM + (k - UNITS);
    const float4 v0 = ((const float4*)src)[0];
    const float4 v1 = ((const float4*)src)[1];
    P8 o;
    o.e[0] = __float2bfloat16(v0.x); o.e[1] = __float2bfloat16(v0.y);
    o.e[2] = __float2bfloat16(v0.z); o.e[3] = __float2bfloat16(v0.w);
    o.e[4] = __float2bfloat16(v1.x); o.e[5] = __float2bfloat16(v1.y);
    o.e[6] = __float2bfloat16(v1.z); o.e[7] = __float2bfloat16(v1.w);
    *(bf16x8*)(A + (size_t)r * KTOT + k) = o.v;
  } else {
    const int b  = blockIdx.x - NBLK_A;   // 0..3071
    const int kb = b >> 7;                // 0..23
    const int nb = b & 127;               // 0..127
    const int k0 = kb * 64, n0 = nb * 32;
    const int n4 = (tid & 7) * 4;
    const int kk = tid >> 3;              // 0..31
#pragma unroll
    for (int rr = 0; rr < 64; rr += 32) {
      const float4 v = *(const float4*)(W + (size_t)(k0 + kk + rr) * NGATE + n0 + n4);
      tile[n4 + 0][kk + rr] = v.x; tile[n4 + 1][kk + rr] = v.y;
      tile[n4 + 2][kk + rr] = v.z; tile[n4 + 3][kk + rr] = v.w;
    }
    __syncthreads();
    const int n  = tid >> 3;
    const int k8 = (tid & 7) * 8;
    P8 o;
#pragma unroll
    for (int j = 0; j < 8; ++j) o.e[j] = __float2bfloat16(tile[n][k8 + j]);
    *(bf16x8*)(Wt + (size_t)(n0 + n) * KTOT + k0 + k8) = o.v;
  }
}

// ---------------------------------------------------------------------------
// GEMM + fused LSTM -- R0 structure (the measured optimum), restored.
//
// Ledger of measured alternatives (do not retry):
//   R1 counted-vmcnt K-half pipeline: +4.7us (3.1M bank conflicts from the
//      4-slot swizzle; neutral after backout) -> schedule polish is null here.
//   R2 512-thr / 4 waves/SIMD: neutral -> not occupancy-bound.
//   R3 acc[8][4] @ 1 block/CU: +11us -> 2 co-resident blocks are what hide
//      barrier-drain + L2 latency (m114 mechanism); never drop below 2.
//   R4 cooperative prep+gemm fusion: +141us -> prep needs its 4608-block
//      parallelism.
// Regime: per-CU LDS traffic 192 KB/iter x 24 = 4.6 MB -> ~74 B/cyc/CU
// in-graph = ~87% of the measured 85 B/cyc ds_read_b128 ceiling (m134).
// At the LDS-port roofline for a 64x64-wave-tile structure; fatter tiles
// need >64KB LDS/block which forces 1 block/CU (R3: worse).
//
// Grid 512 (2 blocks/CU). Block tile: 128 rows x 32 units (x4 gates = 128
// virtual cols). 4 waves tile 2x2: wave = 64 rows x 16 units x 4 gates ->
// acc[4][4]. All 4 gates in-lane -> register-local LSTM epilogue.
// A AND B double-buffered in LDS (4 x 16 KB); prefetch iter k+1 via
// global_load_lds(width=16) BEFORE computing iter k; one __syncthreads/iter.
// 16B chunks XOR-swizzled chunk(row,k8)=row*8+(k8^(row&7)) -> 2 lanes/bank
// (free, m136); measured 0 conflicts. Source-side pre-swizzle keeps the
// global_load_lds destination linear (m104/m173).
// XCD: XCD = bi%8 = ub%8 -> co-XCD blocks share the ub B-slice (L2-resident).
// R5 polish: last iter peeled; 16 c_tm1 loads hoisted before the final
// 32-MFMA burst so their L2 latency hides under compute.
// ---------------------------------------------------------------------------
__global__ __launch_bounds__(256, 2) void lstm_gemm(
    const __hip_bfloat16* __restrict__ A,
    const __hip_bfloat16* __restrict__ Wt,
    const float* __restrict__ c_tm1,
    float* __restrict__ out) {
  __shared__ __attribute__((aligned(128))) char lds[4 * 16384];  // A0 A1 B0 B1

  const int tid  = threadIdx.x;
  const int w    = tid >> 6;     // wave 0..3 (uniform)
  const int lane = tid & 63;
  const int quad = lane >> 4;
  const int m16  = lane & 15;
  const int wr   = w >> 1;       // row half (0,1)
  const int wu   = w & 1;        // unit half (0,1)

  const int mb = blockIdx.x >> 5;   // 0..15
  const int ub = blockIdx.x & 31;   // 0..31  (XCD = ub % 8)
  const int m0 = mb * 128;
  const int u0 = ub * 32;

  // Staging: 2048 16B chunks per iter (A 1024 + B 1024) / 256 thr = 8 each.
  const __hip_bfloat16* ptr[8];
  int dst[8];
#pragma unroll
  for (int s = 0; s < 8; ++s) {
    const int q  = s * 4 + w;              // wave-uniform 0..31
    const int ci = (q & 15) * 64 + lane;   // chunk 0..1023 within tile
    const int row = ci >> 3;               // 0..127
    const int k8  = (ci & 7) ^ (row & 7);  // source-side swizzle
    if (q < 16) {   // A tile
      ptr[s] = A + (size_t)(m0 + row) * KTOT + k8 * 8;
      dst[s] = q * 1024;                   // within A buffer
    } else {        // B tile: virtual col row -> Wt row
      const int wrow = ((row >> 5) << 10) + u0 + (row & 31);
      ptr[s] = Wt + (size_t)wrow * KTOT + k8 * 8;
      dst[s] = 32768 + (q - 16) * 1024;    // within B buffer 0
    }
  }

  f32x4 acc[4][4];
#pragma unroll
  for (int i = 0; i < 4; ++i)
#pragma unroll
    for (int g = 0; g < 4; ++g) {
      f32x4 z = {0.f, 0.f, 0.f, 0.f};
      acc[i][g] = z;
    }

  auto compute = [&](int cur) {
    const char* abuf = lds + cur * 16384;
    const char* bbuf = lds + 32768 + cur * 16384;
#pragma unroll
    for (int t = 0; t < 2; ++t) {
      bf16x8 a[4], b[4];
#pragma unroll
      for (int i = 0; i < 4; ++i) {
        const int row  = wr * 64 + i * 16 + m16;
        const int slot = (t * 4 + quad) ^ (row & 7);
        a[i] = *(const bf16x8*)(abuf + (row * 8 + slot) * 16);
      }
#pragma unroll
      for (int g = 0; g < 4; ++g) {
        const int vr   = g * 32 + wu * 16 + m16;
        const int slot = (t * 4 + quad) ^ (vr & 7);
        b[g] = *(const bf16x8*)(bbuf + (vr * 8 + slot) * 16);
      }
#pragma unroll
      for (int g = 0; g < 4; ++g)
#pragma unroll
        for (int i = 0; i < 4; ++i)
          acc[i][g] = __builtin_amdgcn_mfma_f32_16x16x32_bf16(a[i], b[g], acc[i][g], 0, 0, 0);
    }
  };

  // prologue: stage iter 0 into buffer 0
#pragma unroll
  for (int s = 0; s < 8; ++s)
    __builtin_amdgcn_global_load_lds(AS1(ptr[s]), AS3(lds + dst[s]), 16, 0, 0);
  __syncthreads();

  for (int it = 0; it < NITER - 1; ++it) {
    const int cur = it & 1;
    const int nxt = cur ^ 1;
    const int koff = (it + 1) * BK;
#pragma unroll
    for (int s = 0; s < 8; ++s)
      __builtin_amdgcn_global_load_lds(AS1(ptr[s] + koff),
                                       AS3(lds + dst[s] + nxt * 16384), 16, 0, 0);
    compute(cur);
    __syncthreads();   // drains prefetch writes + fences reads of `cur`
  }

  // peeled last iter: hoist c_tm1 loads so L2 latency hides under the MFMAs
  const int u = u0 + wu * 16 + m16;
  float cpre[4][4];
#pragma unroll
  for (int i = 0; i < 4; ++i)
#pragma unroll
    for (int reg = 0; reg < 4; ++reg) {
      const int r = m0 + wr * 64 + i * 16 + quad * 4 + reg;
      cpre[i][reg] = c_tm1[(size_t)r * UNITS + u];
    }
  compute((NITER - 1) & 1);

  // fused LSTM epilogue -- all 4 gates in-lane
#pragma unroll
  for (int i = 0; i < 4; ++i)
#pragma unroll
    for (int reg = 0; reg < 4; ++reg) {
      const int r = m0 + wr * 64 + i * 16 + quad * 4 + reg;
      const float z0 = acc[i][0][reg];   // gate i
      const float z1 = acc[i][1][reg];   // gate f
      const float z2 = acc[i][2][reg];   // c_tilde
      const float z3 = acc[i][3][reg];   // gate o
      const float ig = 1.f / (1.f + __expf(-z0));
      const float fg = 1.f / (1.f + __expf(-z1));
      const float ct = 1.f - 2.f / (__expf(2.f * z2) + 1.f);   // tanh, inf-safe
      const float og = 1.f / (1.f + __expf(-z3));
      const float cc = fg * cpre[i][reg] + ig * ct;
      const float hh = og * (1.f - 2.f / (__expf(2.f * cc) + 1.f));
      out[(size_t)r * UNITS + u] = hh;
      out[(size_t)BATCH * UNITS + (size_t)r * UNITS + u] = cc;
    }
}

// ---------------------------------------------------------------------------
// Fallback (only if d_ws too small): naive fp32, correct but slow.
// ---------------------------------------------------------------------------
__global__ __launch_bounds__(256) void lstm_naive(
    const float* __restrict__ x, const float* __restrict__ h,
    const float* __restrict__ c_tm1, const float* __restrict__ W,
    float* __restrict__ out) {
  int idx = blockIdx.x * 256 + threadIdx.x;
  int r = idx / UNITS;
  int u = idx % UNITS;
  float z[4] = {0.f, 0.f, 0.f, 0.f};
  for (int k = 0; k < KTOT; ++k) {
    float a = (k < UNITS) ? h[(size_t)r * UNITS + k] : x[(size_t)r * IDIM + k - UNITS];
#pragma unroll
    for (int g = 0; g < 4; ++g)
      z[g] += a * W[(size_t)k * NGATE + g * UNITS + u];
  }
  float ig = 1.f / (1.f + __expf(-z[0]));
  float fg = 1.f / (1.f + __expf(-z[1]));
  float ct = 1.f - 2.f / (__expf(2.f * z[2]) + 1.f);
  float og = 1.f / (1.f + __expf(-z[3]));
  float cc = fg * c_tm1[(size_t)r * UNITS + u] + ig * ct;
  float hh = og * (1.f - 2.f / (__expf(2.f * cc) + 1.f));
  out[(size_t)r * UNITS + u] = hh;
  out[(size_t)BATCH * UNITS + (size_t)r * UNITS + u] = cc;
}

extern "C" void kernel_launch(void* const* d_in, const int* in_sizes, int n_in,
                              void* d_out, int out_size, void* d_ws, size_t ws_size,
                              hipStream_t stream) {
  const float* x = (const float*)d_in[0];   // [2048][512]
  const float* h = (const float*)d_in[1];   // [2048][1024]
  const float* c = (const float*)d_in[2];   // [2048][1024]
  const float* W = (const float*)d_in[3];   // [1536][4096]
  float* out = (float*)d_out;               // h then c, 2 x [2048][1024]

  const size_t needA  = (size_t)BATCH * KTOT * sizeof(__hip_bfloat16);  // 6.29 MB
  const size_t needWt = (size_t)NGATE * KTOT * sizeof(__hip_bfloat16);  // 12.58 MB
  if (ws_size < needA + needWt) {
    hipLaunchKernelGGL(lstm_naive, dim3((BATCH * UNITS) / 256), dim3(256), 0, stream,
                       x, h, c, W, out);
    return;
  }

  __hip_bfloat16* A  = (__hip_bfloat16*)d_ws;
  __hip_bfloat16* Wt = (__hip_bfloat16*)((char*)d_ws + needA);

  hipLaunchKernelGGL(prep, dim3(NBLK_A + NBLK_T), dim3(256), 0, stream, x, h, W, A, Wt);
  hipLaunchKernelGGL(lstm_gemm, dim3(512), dim3(256), 0, stream, A, Wt, c, out);
}